// Round 1
// baseline (54.311 us; speedup 1.0000x reference)
//
#include <hip/hip_runtime.h>

// DerivativeNet: masked 1-D finite difference along last axis.
// u: (8,4,1024,1024) f32, nmask: (1,1,1024,1024) f32 (broadcast over batch).
// out[i] = eroded*central + edge1*left + edge2*right  (h = 0.01)
// Memory-bound: ~260 MiB traffic -> target ~41 us @ 6.3 TB/s.

#define W 1024
#define HINV 100.0f        // 1/h
#define HINV2 50.0f        // 1/(2h)

__global__ __launch_bounds__(256)
void deriv_kernel(const float* __restrict__ u,
                  const float* __restrict__ nmask,
                  float* __restrict__ out) {
    const int r = blockIdx.x;          // row index over 8*4*1024 rows
    const int x = threadIdx.x * 4;     // 4 elements per thread, W=1024 = 256*4
    const int y = r & (W - 1);         // mask row (broadcast over batch dims)

    const float* urow = u + (size_t)r * W;
    const float* mrow = nmask + (size_t)y * W;

    // center vectors
    const float4 uc = *(const float4*)(urow + x);
    const float4 mc = *(const float4*)(mrow + x);

    // halo scalars (zero-padded boundaries)
    const float u_m1 = (x == 0) ? 0.0f : urow[x - 1];
    const float u_p4 = (x + 4 >= W) ? 0.0f : urow[x + 4];
    const float m_m1 = (x == 0) ? 0.0f : mrow[x - 1];
    const float m_p4 = (x + 4 >= W) ? 0.0f : mrow[x + 4];

    // per-element arrays for clean indexing (compiler keeps in regs)
    float uv[6] = { u_m1, uc.x, uc.y, uc.z, uc.w, u_p4 };
    float mv[6] = { m_m1, mc.x, mc.y, mc.z, mc.w, m_p4 };

    float4 o;
    float* op = &o.x;
    #pragma unroll
    for (int j = 0; j < 4; ++j) {
        const float ul = uv[j];        // u[i-1]
        const float uu = uv[j + 1];    // u[i]
        const float ur = uv[j + 2];    // u[i+1]
        const float ml = mv[j];
        const float mm = mv[j + 1];
        const float mr = mv[j + 2];

        const float internal_d = (ur - ul) * HINV2;
        const float left_d     = (ur - uu) * HINV;
        const float right_d    = (uu - ul) * HINV;

        const float eroded = (ml + mm + mr == 3.0f) ? 1.0f : 0.0f;
        const float edge1  = (mm - ml == 1.0f)      ? 1.0f : 0.0f;
        const float edge2  = (mr - mm == -1.0f)     ? 1.0f : 0.0f;

        op[j] = eroded * internal_d + edge1 * left_d + edge2 * right_d;
    }

    *(float4*)(out + (size_t)r * W + x) = o;
}

extern "C" void kernel_launch(void* const* d_in, const int* in_sizes, int n_in,
                              void* d_out, int out_size, void* d_ws, size_t ws_size,
                              hipStream_t stream) {
    const float* u = (const float*)d_in[0];
    const float* nmask = (const float*)d_in[1];
    float* out = (float*)d_out;

    const int rows = in_sizes[0] / W;   // 8*4*1024 = 32768
    deriv_kernel<<<rows, 256, 0, stream>>>(u, nmask, out);
}

// Round 2
// 51.699 us; speedup vs baseline: 1.0505x; 1.0505x over previous
//
#include <hip/hip_runtime.h>

// DerivativeNet: masked 1-D finite difference along last axis.
// u: (8,4,1024,1024) f32, nmask: (1,1,1024,1024) f32 broadcast over the 32
// batch rows. Key structure: rows r and r+1024*k share mask row y = r&1023.
// Each block owns one mask row group: compute per-element linear coefficients
// from the mask ONCE, then stream 16 batch rows through them.
//   out[i] = er*(u[i+1]-u[i-1])*50 + e1*(u[i+1]-u[i])*100 + e2*(u[i]-u[i-1])*100
//          = ca*u[i+1] + cb*u[i] + cc*u[i-1]
//   ca = 50*er + 100*e1, cb = 100*(e2-e1), cc = -50*er - 100*e2
// Memory-bound: ~260 MiB -> ~41 us floor @ 6.3 TB/s copy ceiling.

#define W 1024
#define NBATCH 32          // 8*4 broadcast rows per mask row
#define RPB 16             // batch rows per block (2 blocks per mask group)

typedef float f32x4 __attribute__((ext_vector_type(4)));

__global__ __launch_bounds__(256)
void deriv_kernel(const float* __restrict__ u,
                  const float* __restrict__ nmask,
                  float* __restrict__ out) {
    const int b = blockIdx.x;
    const int y = b >> 1;                  // mask row 0..1023
    const int k0 = (b & 1) * RPB;          // batch-row start (0 or 16)
    const int x = threadIdx.x * 4;         // 4 contiguous elements per thread

    // ---- mask -> coefficients (once per block) ----
    const float* mrow = nmask + (size_t)y * W;
    const f32x4 mc = *(const f32x4*)(mrow + x);
    const float m_m1 = (x == 0) ? 0.0f : mrow[x - 1];
    const float m_p4 = (x + 4 >= W) ? 0.0f : mrow[x + 4];
    float mv[6] = { m_m1, mc[0], mc[1], mc[2], mc[3], m_p4 };

    float ca[4], cb[4], cc[4];
    #pragma unroll
    for (int j = 0; j < 4; ++j) {
        const float er = (mv[j] + mv[j+1] + mv[j+2] == 3.0f) ? 1.0f : 0.0f;
        const float e1 = (mv[j+1] - mv[j]   ==  1.0f) ? 1.0f : 0.0f;
        const float e2 = (mv[j+2] - mv[j+1] == -1.0f) ? 1.0f : 0.0f;
        ca[j] =  50.0f * er + 100.0f * e1;   // coeff of u[i+1]
        cb[j] = 100.0f * (e2 - e1);          // coeff of u[i]
        cc[j] = -50.0f * er - 100.0f * e2;   // coeff of u[i-1]
    }

    const bool left_edge  = (x == 0);
    const bool right_edge = (x + 4 >= W);

    // ---- stream batch rows through the coefficients ----
    #pragma unroll 4
    for (int k = k0; k < k0 + RPB; ++k) {
        const size_t row_off = ((size_t)k * W + y) * W;   // row r = k*1024 + y
        const float* urow = u + row_off;

        const f32x4 uc = *(const f32x4*)(urow + x);
        const float u_m1 = left_edge  ? 0.0f : urow[x - 1];
        const float u_p4 = right_edge ? 0.0f : urow[x + 4];
        float uv[6] = { u_m1, uc[0], uc[1], uc[2], uc[3], u_p4 };

        f32x4 o;
        #pragma unroll
        for (int j = 0; j < 4; ++j) {
            o[j] = ca[j] * uv[j+2] + cb[j] * uv[j+1] + cc[j] * uv[j];
        }

        __builtin_nontemporal_store(o, (f32x4*)(out + row_off + x));
    }
}

extern "C" void kernel_launch(void* const* d_in, const int* in_sizes, int n_in,
                              void* d_out, int out_size, void* d_ws, size_t ws_size,
                              hipStream_t stream) {
    const float* u = (const float*)d_in[0];
    const float* nmask = (const float*)d_in[1];
    float* out = (float*)d_out;

    const int rows = in_sizes[0] / W;            // 32768
    const int blocks = rows / RPB;               // 2048
    deriv_kernel<<<blocks, 256, 0, stream>>>(u, nmask, out);
}